// Round 2
// 1199.278 us; speedup vs baseline: 1.1259x; 1.1259x over previous
//
#include <hip/hip_runtime.h>

// Problem sizes
// B=8 M=4 T=2048 E=768 P=256 K=64 V=64 H=128 NEXP=16 COMB=384 HID=192
// tokens NT = 65536, sequences NSEQ = 32
// (Round 2: resubmission of round-1 kernel — bench infra failed, no signal.)

typedef unsigned short u16;
typedef float f32x4 __attribute__((ext_vector_type(4)));
typedef short s16x8 __attribute__((ext_vector_type(8)));
typedef unsigned u32x2 __attribute__((ext_vector_type(2)));

#define DI static __device__ __forceinline__

DI u16 f2b(float f) {  // fp32 -> bf16 RNE
  unsigned u = __builtin_bit_cast(unsigned, f);
  u += 0x7fffu + ((u >> 16) & 1u);
  return (u16)(u >> 16);
}
DI float b2f(u16 s) { return __builtin_bit_cast(float, ((unsigned)s) << 16); }
DI float rcp_fast(float x) { return __builtin_amdgcn_rcpf(x); }
DI f32x4 mfma16(s16x8 a, s16x8 b, f32x4 c) {
  return __builtin_amdgcn_mfma_f32_16x16x32_bf16(a, b, c, 0, 0, 0);
}

// ---- workspace layout (bytes) ----
#define OFF_COMB   0ull            // u16 [65536][384]  (proc | rus)      50331648
#define OFF_URS    50331648ull     // f32 [32][2048][4] {U, rbar, sbar, 0} 1048576
#define OFF_TPWB   51380736ull     // u16 [256][768]                        393216
#define OFF_WHHB   51773952ull     // u16 [384][128]                         98304
#define OFF_W1B    51872256ull     // u16 [192][384]                        147456
#define OFF_W2B    52019712ull     // u16 [16][192]                           6144
#define OFF_WABC   52025856ull     // f32 wA[256] wB[256] wC[256]             3072
#define OFF_CABC   52028928ull     // f32 cA cB cC pad                          16
#define OFF_GX     52028944ull     // f32 gxu[384] gxr[384] gxs[384] gxc[384] 6144

// =====================================================================
// K0: derived weights + bf16 conversions
// gx const row folds b_hh for the r and z gates (the recurrent-side
// bias is a plain additive constant for those gates; for the n gate it
// must stay with hn since r multiplies it).
// =====================================================================
__global__ __launch_bounds__(512) void k_prep(
    const float* __restrict__ qw, const float* __restrict__ qb,
    const float* __restrict__ kw, const float* __restrict__ kb,
    const float* __restrict__ vw, const float* __restrict__ vb,
    const float* __restrict__ wih, const float* __restrict__ bih,
    const float* __restrict__ bhh,
    const float* __restrict__ tpw, const float* __restrict__ whh,
    const float* __restrict__ w1, const float* __restrict__ w2,
    u16* __restrict__ tpwb, u16* __restrict__ whhb,
    u16* __restrict__ w1b, u16* __restrict__ w2b,
    float* __restrict__ wabc, float* __restrict__ cabc, float* __restrict__ gx) {
  const int tid = threadIdx.x, bid = blockIdx.x;
  if (bid == 0 && tid < 256) {
    int p = tid;
    float a = 0.f, b = 0.f, c = 0.f;
    for (int j = 0; j < 64; j++) {
      float q = qw[j * 256 + p];
      a += q * kw[2 * j]; b += q * kw[2 * j + 1]; c += q * kb[j];
    }
    wabc[p] = a; wabc[256 + p] = b; wabc[512 + p] = c;
    if (p == 0) {
      float ca = 0.f, cb = 0.f, cc = 0.f;
      for (int j = 0; j < 64; j++) {
        ca += qb[j] * kw[2 * j]; cb += qb[j] * kw[2 * j + 1]; cc += qb[j] * kb[j];
      }
      cabc[0] = ca; cabc[1] = cb; cabc[2] = cc; cabc[3] = 0.f;
    }
  }
  if (bid == 1 && tid < 384) {
    int j = tid;
    float r = 0.f, s = 0.f, c0 = 0.f;
    for (int v = 0; v < 64; v++) {
      float w = wih[j * 65 + 1 + v];
      r += w * vw[2 * v]; s += w * vw[2 * v + 1]; c0 += w * vb[v];
    }
    gx[j] = wih[j * 65]; gx[384 + j] = r; gx[768 + j] = s;
    gx[1152 + j] = c0 + bih[j] + (j < 256 ? bhh[j] : 0.f);
  }
  const int n1 = 768 * 256, n2 = 384 * 128, n3 = 192 * 384, n4 = 16 * 192;
  const int total = n1 + n2 + n3 + n4;
  for (int i = bid * blockDim.x + tid; i < total; i += gridDim.x * blockDim.x) {
    if (i < n1) tpwb[i] = f2b(tpw[i]);
    else if (i < n1 + n2) whhb[i - n1] = f2b(whh[i - n1]);
    else if (i < n1 + n2 + n3) w1b[i - n1 - n2] = f2b(w1[i - n1 - n2]);
    else w2b[i - n1 - n2 - n3] = f2b(w2[i - n1 - n2 - n3]);
  }
}

// =====================================================================
// K1: processed = relu(TE @ tp_w.T + tp_b)  -> comb[:, 0:256] (bf16)
// 128x256 tile per block, BK=64, bf16 MFMA, XOR-swizzled LDS
// =====================================================================
__global__ __launch_bounds__(512, 1) void k_gemm1(
    const float* __restrict__ te, const float* __restrict__ tpb,
    const u16* __restrict__ tpwb, u16* __restrict__ comb) {
  __shared__ u16 Als[128 * 64];
  __shared__ u16 Bls[256 * 64];
  const int tid = threadIdx.x;
  const int lane = tid & 63, w = tid >> 6;
  const int c = lane & 15, g4 = lane >> 4;
  const int wm = w >> 2, wn = w & 3;
  const long row0 = (long)blockIdx.x * 128;

  f32x4 acc[4][4];
  #pragma unroll
  for (int i = 0; i < 4; i++)
    #pragma unroll
    for (int j = 0; j < 4; j++) acc[i][j] = (f32x4)(0.f);

  for (int kk = 0; kk < 12; kk++) {
    // stage A (fp32 -> bf16 inline)
    #pragma unroll
    for (int ii = 0; ii < 2; ii++) {
      int idx = tid + 512 * ii;
      int row = idx >> 3, kb = idx & 7;
      const float* g = te + (row0 + row) * 768 + kk * 64 + kb * 8;
      f32x4 p0 = *(const f32x4*)g;
      f32x4 p1 = *(const f32x4*)(g + 4);
      s16x8 v;
      v[0] = f2b(p0[0]); v[1] = f2b(p0[1]); v[2] = f2b(p0[2]); v[3] = f2b(p0[3]);
      v[4] = f2b(p1[0]); v[5] = f2b(p1[1]); v[6] = f2b(p1[2]); v[7] = f2b(p1[3]);
      *(s16x8*)&Als[row * 64 + ((kb ^ (row & 7)) << 3)] = v;
    }
    // stage B
    #pragma unroll
    for (int ii = 0; ii < 4; ii++) {
      int idx = tid + 512 * ii;
      int n = idx >> 3, kb = idx & 7;
      s16x8 v = *(const s16x8*)(tpwb + n * 768 + kk * 64 + kb * 8);
      *(s16x8*)&Bls[n * 64 + ((kb ^ (n & 7)) << 3)] = v;
    }
    __syncthreads();
    #pragma unroll
    for (int kt = 0; kt < 2; kt++) {
      s16x8 af[4], bf[4];
      #pragma unroll
      for (int mt = 0; mt < 4; mt++) {
        int row = wm * 64 + mt * 16 + c;
        af[mt] = *(const s16x8*)&Als[row * 64 + (((kt * 4 + g4) ^ (row & 7)) << 3)];
      }
      #pragma unroll
      for (int nt = 0; nt < 4; nt++) {
        int n = wn * 64 + nt * 16 + c;
        bf[nt] = *(const s16x8*)&Bls[n * 64 + (((kt * 4 + g4) ^ (n & 7)) << 3)];
      }
      #pragma unroll
      for (int mt = 0; mt < 4; mt++)
        #pragma unroll
        for (int nt = 0; nt < 4; nt++)
          acc[mt][nt] = mfma16(af[mt], bf[nt], acc[mt][nt]);
    }
    __syncthreads();
  }
  #pragma unroll
  for (int nt = 0; nt < 4; nt++) {
    int col = wn * 64 + nt * 16 + c;
    float bias = tpb[col];
    #pragma unroll
    for (int mt = 0; mt < 4; mt++)
      #pragma unroll
      for (int r = 0; r < 4; r++) {
        long row = row0 + wm * 64 + mt * 16 + g4 * 4 + r;
        float v = fmaxf(acc[mt][nt][r] + bias, 0.f);
        comb[row * 384 + col] = f2b(v);
      }
  }
}

// =====================================================================
// K2: collapsed attention. Per token: 3 dots of 256, softmax over 3
// "others", emit (U, rbar, sbar). One wave per token.
// urs layout: [seq][t][4] (seq-major so k_gru can bulk-load its slice)
// =====================================================================
__global__ __launch_bounds__(256) void k_attn(
    const u16* __restrict__ comb, const float* __restrict__ U,
    const float* __restrict__ R, const float* __restrict__ S,
    const float* __restrict__ wabc, const float* __restrict__ cabc,
    float* __restrict__ urs) {
  const int lane = threadIdx.x & 63;
  const long token = (long)blockIdx.x * 4 + (threadIdx.x >> 6);
  const int t = (int)(token & 2047);
  const int seq = (int)(token >> 11);
  const int m = seq & 3;

  u32x2 pv = *(const u32x2*)(comb + token * 384 + lane * 4);
  float p0 = __builtin_bit_cast(float, pv[0] << 16);
  float p1 = __builtin_bit_cast(float, pv[0] & 0xffff0000u);
  float p2 = __builtin_bit_cast(float, pv[1] << 16);
  float p3 = __builtin_bit_cast(float, pv[1] & 0xffff0000u);
  f32x4 wa = *(const f32x4*)(wabc + lane * 4);
  f32x4 wb = *(const f32x4*)(wabc + 256 + lane * 4);
  f32x4 wc = *(const f32x4*)(wabc + 512 + lane * 4);
  float a = p0 * wa[0] + p1 * wa[1] + p2 * wa[2] + p3 * wa[3];
  float b = p0 * wb[0] + p1 * wb[1] + p2 * wb[2] + p3 * wb[3];
  float cd = p0 * wc[0] + p1 * wc[1] + p2 * wc[2] + p3 * wc[3];
  #pragma unroll
  for (int off = 32; off; off >>= 1) {
    a += __shfl_xor(a, off); b += __shfl_xor(b, off); cd += __shfl_xor(cd, off);
  }
  a += cabc[0]; b += cabc[1]; cd += cabc[2];

  float rv[3], sv[3], sc[3];
  #pragma unroll
  for (int n = 0; n < 3; n++) {
    int o = n + (n >= m ? 1 : 0);
    long idx = ((long)seq * 4 + o) * 2048 + t;
    rv[n] = R[idx]; sv[n] = S[idx];
    sc[n] = (a * rv[n] + b * sv[n] + cd) * 0.125f;
  }
  float mx = fmaxf(sc[0], fmaxf(sc[1], sc[2]));
  float e0 = __expf(sc[0] - mx), e1 = __expf(sc[1] - mx), e2 = __expf(sc[2] - mx);
  float inv = rcp_fast(e0 + e1 + e2);
  float rb = (e0 * rv[0] + e1 * rv[1] + e2 * rv[2]) * inv;
  float sb = (e0 * sv[0] + e1 * sv[1] + e2 * sv[2]) * inv;
  if (lane == 0) {
    f32x4 v; v[0] = U[token]; v[1] = rb; v[2] = sb; v[3] = 0.f;
    *(f32x4*)(urs + ((long)seq * 2048 + t) * 4) = v;
  }
}

// =====================================================================
// K3: GRU scan. 1 block per sequence (32 blocks), 8 waves (512 thr).
// Wave w owns the gate-triple of j-tile w: MFMA n-tiles {w, 8+w, 16+w},
// so each wave issues 12 MFMAs/step (was 24) and each lane computes ONE
// gate triplet for j = w*16 + c (was two). Still 1 barrier/step, h
// double-buffered in LDS, urs slice LDS-resident, 32-step hist flush.
// =====================================================================
__global__ __launch_bounds__(512, 1) void k_gru(
    const u16* __restrict__ whhb, const float* __restrict__ bhh,
    const float* __restrict__ gx, const float* __restrict__ urs,
    u16* __restrict__ comb) {
  __shared__ u16 hbuf[2][128];
  __shared__ u16 hist[2][32][128];   // 16 KB history chunks
  __shared__ float ulds[2048][4];    // 32 KB urs slice for this seq
  const int tid = threadIdx.x;
  const int lane = tid & 63, w = tid >> 6;   // w in 0..7
  const int c = lane & 15, g4 = lane >> 4;
  const int seq = blockIdx.x;

  // one-time bulk load of this sequence's urs slice (contiguous 32 KB)
  for (int i = tid; i < 2048; i += 512)
    *(f32x4*)&ulds[i][0] = *(const f32x4*)(urs + ((long)seq * 2048 + i) * 4);

  const int j = w * 16 + c;                  // this lane's H column (0..127)
  // B-fragments for the three gate rows at column j: n = g*128 + j
  s16x8 bfr[3][4];
  #pragma unroll
  for (int g = 0; g < 3; g++) {
    int n = g * 128 + j;
    #pragma unroll
    for (int kt = 0; kt < 4; kt++)
      bfr[g][kt] = *(const s16x8*)(whhb + n * 128 + kt * 32 + g4 * 8);
  }
  float gxv[3][4];
  #pragma unroll
  for (int g = 0; g < 3; g++) {
    int jj = g * 128 + j;
    gxv[g][0] = gx[jj];        gxv[g][1] = gx[384 + jj];
    gxv[g][2] = gx[768 + jj];  gxv[g][3] = gx[1152 + jj];
  }
  const float bhn = bhh[256 + j];   // n-gate recurrent bias (stays with hn)

  if (tid < 128) { hbuf[0][tid] = 0; hbuf[1][tid] = 0; }
  float hprev = 0.f;
  __syncthreads();  // drains the one-time urs preload too

  u16* rbase = comb + (long)seq * 2048 * 384 + 256;
  for (int chunk = 0; chunk < 64; chunk++) {
    #pragma unroll 2
    for (int s = 0; s < 32; s++) {
      const int t = chunk * 32 + s;
      f32x4 ucur = *(const f32x4*)&ulds[t][0];  // LDS broadcast, no vmem
      s16x8 af[4];
      #pragma unroll
      for (int kt = 0; kt < 4; kt++)
        af[kt] = *(const s16x8*)&hbuf[t & 1][kt * 32 + g4 * 8];
      // 6 independent depth-2 MFMA chains (12 MFMAs total per wave)
      f32x4 aA[3], aB[3];
      #pragma unroll
      for (int g = 0; g < 3; g++) {
        f32x4 x0 = (f32x4)(0.f), x1 = (f32x4)(0.f);
        x0 = mfma16(af[0], bfr[g][0], x0);
        x1 = mfma16(af[2], bfr[g][2], x1);
        x0 = mfma16(af[1], bfr[g][1], x0);
        x1 = mfma16(af[3], bfr[g][3], x1);
        aA[g] = x0; aB[g] = x1;
      }
      float uu = ucur[0], rbv = ucur[1], sbv = ucur[2];
      float xr = gxv[0][3] + uu * gxv[0][0] + rbv * gxv[0][1] + sbv * gxv[0][2];
      float xz = gxv[1][3] + uu * gxv[1][0] + rbv * gxv[1][1] + sbv * gxv[1][2];
      float xn = gxv[2][3] + uu * gxv[2][0] + rbv * gxv[2][1] + sbv * gxv[2][2];
      float hr = aA[0][0] + aB[0][0];   // b_hh_r folded into gx const
      float hz = aA[1][0] + aB[1][0];   // b_hh_z folded into gx const
      float hn = aA[2][0] + aB[2][0] + bhn;
      float r = rcp_fast(1.f + __expf(-(xr + hr)));
      float z = rcp_fast(1.f + __expf(-(xz + hz)));
      float e = __expf(2.f * (xn + r * hn));
      float n = 1.f - 2.f * rcp_fast(e + 1.f);
      float h = z * (hprev - n) + n;
      hprev = h;
      if (g4 == 0) {
        u16 hb = f2b(h);
        hbuf[(t + 1) & 1][j] = hb;
        hist[chunk & 1][s][j] = hb;
      }
      __syncthreads();
    }
    // flush chunk history: 32 rows x 256 B, coalesced 16 B stores,
    // fire-and-forget (512 threads cover the 8 KB chunk in one shot)
    const int t0 = chunk * 32;
    {
      int row = tid >> 4, part = tid & 15;
      s16x8 v = *(const s16x8*)&hist[chunk & 1][row][part * 8];
      *(s16x8*)(rbase + (long)(t0 + row) * 384 + part * 8) = v;
    }
  }
}

// =====================================================================
// K4: fused MLP: hid = relu(comb @ w1.T + b1) (bf16 via LDS), then
// logits = hid @ w2.T + b2 (fp32 out). 128 rows per block.
// =====================================================================
__global__ __launch_bounds__(512, 1) void k_mlp(
    const u16* __restrict__ comb, const u16* __restrict__ w1b,
    const float* __restrict__ b1, const u16* __restrict__ w2b,
    const float* __restrict__ b2, float* __restrict__ out) {
  __shared__ u16 smem[40960];  // 80 KB
  u16* Als = smem;             // 128x128
  u16* Bls = smem + 16384;     // 192x128
  u16* Hls = smem;             // 128x192 (reuse after barrier)
  const int tid = threadIdx.x;
  const int lane = tid & 63, w = tid >> 6;
  const int c = lane & 15, g4 = lane >> 4;
  const int wm = w >> 2, wn = w & 3;
  const long row0 = (long)blockIdx.x * 128;

  s16x8 w2f[6];
  #pragma unroll
  for (int kt = 0; kt < 6; kt++)
    w2f[kt] = *(const s16x8*)(w2b + c * 192 + kt * 32 + g4 * 8);
  const float b2v = b2[c];

  f32x4 acc[4][3];
  #pragma unroll
  for (int i = 0; i < 4; i++)
    #pragma unroll
    for (int j = 0; j < 3; j++) acc[i][j] = (f32x4)(0.f);

  for (int kc = 0; kc < 3; kc++) {
    #pragma unroll
    for (int ii = 0; ii < 4; ii++) {
      int idx = tid + 512 * ii;
      int row = idx >> 4, kb = idx & 15;
      s16x8 v = *(const s16x8*)(comb + (row0 + row) * 384 + kc * 128 + kb * 8);
      *(s16x8*)&Als[row * 128 + ((kb ^ (row & 7)) << 3)] = v;
    }
    #pragma unroll
    for (int ii = 0; ii < 6; ii++) {
      int idx = tid + 512 * ii;
      int n = idx >> 4, kb = idx & 15;
      s16x8 v = *(const s16x8*)(w1b + n * 384 + kc * 128 + kb * 8);
      *(s16x8*)&Bls[n * 128 + ((kb ^ (n & 7)) << 3)] = v;
    }
    __syncthreads();
    #pragma unroll
    for (int kt = 0; kt < 4; kt++) {
      s16x8 af[4], bf[3];
      #pragma unroll
      for (int mt = 0; mt < 4; mt++) {
        int row = wm * 64 + mt * 16 + c;
        af[mt] = *(const s16x8*)&Als[row * 128 + (((kt * 4 + g4) ^ (row & 7)) << 3)];
      }
      #pragma unroll
      for (int nt = 0; nt < 3; nt++) {
        int n = wn * 48 + nt * 16 + c;
        bf[nt] = *(const s16x8*)&Bls[n * 128 + (((kt * 4 + g4) ^ (n & 7)) << 3)];
      }
      #pragma unroll
      for (int mt = 0; mt < 4; mt++)
        #pragma unroll
        for (int nt = 0; nt < 3; nt++)
          acc[mt][nt] = mfma16(af[mt], bf[nt], acc[mt][nt]);
    }
    __syncthreads();
  }
  // hid -> LDS (bf16, swizzled)
  #pragma unroll
  for (int nt = 0; nt < 3; nt++) {
    int col = wn * 48 + nt * 16 + c;
    float bias = b1[col];
    int cb = col >> 3, cl = col & 7;
    #pragma unroll
    for (int mt = 0; mt < 4; mt++)
      #pragma unroll
      for (int r = 0; r < 4; r++) {
        int row = wm * 64 + mt * 16 + g4 * 4 + r;
        float v = fmaxf(acc[mt][nt][r] + bias, 0.f);
        Hls[row * 192 + ((cb ^ (row & 7)) << 3) + cl] = f2b(v);
      }
  }
  __syncthreads();
  // gemm2: 16 outputs, K=192
  f32x4 a2 = (f32x4)(0.f);
  const int row = w * 16 + c, r7 = row & 7;
  #pragma unroll
  for (int kt = 0; kt < 6; kt++) {
    s16x8 af = *(const s16x8*)&Hls[row * 192 + (((kt * 4 + g4) ^ r7) << 3)];
    a2 = mfma16(af, w2f[kt], a2);
  }
  #pragma unroll
  for (int r = 0; r < 4; r++) {
    long grow = row0 + w * 16 + g4 * 4 + r;
    out[grow * 16 + c] = a2[r] + b2v;
  }
}

// =====================================================================
extern "C" void kernel_launch(void* const* d_in, const int* in_sizes, int n_in,
                              void* d_out, int out_size, void* d_ws, size_t ws_size,
                              hipStream_t stream) {
  (void)in_sizes; (void)n_in; (void)out_size; (void)ws_size;
  const float* te  = (const float*)d_in[0];
  const float* U   = (const float*)d_in[1];
  const float* R   = (const float*)d_in[2];
  const float* S   = (const float*)d_in[3];
  const float* tpw = (const float*)d_in[4];
  const float* tpb = (const float*)d_in[5];
  const float* qw  = (const float*)d_in[6];
  const float* qb  = (const float*)d_in[7];
  const float* kw  = (const float*)d_in[8];
  const float* kb  = (const float*)d_in[9];
  const float* vw  = (const float*)d_in[10];
  const float* vb  = (const float*)d_in[11];
  const float* wih = (const float*)d_in[12];
  const float* whh = (const float*)d_in[13];
  const float* bih = (const float*)d_in[14];
  const float* bhh = (const float*)d_in[15];
  const float* w1  = (const float*)d_in[16];
  const float* b1  = (const float*)d_in[17];
  const float* w2  = (const float*)d_in[18];
  const float* b2  = (const float*)d_in[19];

  char* ws = (char*)d_ws;
  u16*   comb = (u16*)(ws + OFF_COMB);
  float* urs  = (float*)(ws + OFF_URS);
  u16*   tpwb = (u16*)(ws + OFF_TPWB);
  u16*   whhb = (u16*)(ws + OFF_WHHB);
  u16*   w1b  = (u16*)(ws + OFF_W1B);
  u16*   w2b  = (u16*)(ws + OFF_W2B);
  float* wabc = (float*)(ws + OFF_WABC);
  float* cabc = (float*)(ws + OFF_CABC);
  float* gx   = (float*)(ws + OFF_GX);
  float* out  = (float*)d_out;

  hipLaunchKernelGGL(k_prep, dim3(32), dim3(512), 0, stream,
                     qw, qb, kw, kb, vw, vb, wih, bih, bhh, tpw, whh, w1, w2,
                     tpwb, whhb, w1b, w2b, wabc, cabc, gx);
  hipLaunchKernelGGL(k_gemm1, dim3(512), dim3(512), 0, stream, te, tpb, tpwb, comb);
  hipLaunchKernelGGL(k_attn, dim3(16384), dim3(256), 0, stream, comb, U, R, S, wabc, cabc, urs);
  hipLaunchKernelGGL(k_gru, dim3(32), dim3(512), 0, stream, whhb, bhh, gx, urs, comb);
  hipLaunchKernelGGL(k_mlp, dim3(512), dim3(512), 0, stream, comb, w1b, b1, w2b, b2, out);
}

// Round 3
// 1185.586 us; speedup vs baseline: 1.1389x; 1.0115x over previous
//
#include <hip/hip_runtime.h>

// Problem sizes
// B=8 M=4 T=2048 E=768 P=256 K=64 V=64 H=128 NEXP=16 COMB=384 HID=192
// tokens NT = 65536, sequences NSEQ = 32
// Round 3: k_gru instruction diet — exp2-prescaled weights, C-seeded bias,
// 1-op bf16 cvt, immediate DS offsets (unroll 8), pipelined x-projection.

typedef unsigned short u16;
typedef float f32x4 __attribute__((ext_vector_type(4)));
typedef short s16x8 __attribute__((ext_vector_type(8)));
typedef unsigned u32x2 __attribute__((ext_vector_type(2)));

#define DI static __device__ __forceinline__

#define L2E  1.44269504088896340736f
#define L2E2 2.88539008177792681472f

DI u16 f2b(float f) {  // fp32 -> bf16 RNE (prep-time use)
  unsigned u = __builtin_bit_cast(unsigned, f);
  u += 0x7fffu + ((u >> 16) & 1u);
  return (u16)(u >> 16);
}
DI u16 f2b_cvt(float f) {  // 1-op hardware convert (hot loop)
  unsigned r;
  asm("v_cvt_pk_bf16_f32 %0, %1, %2" : "=v"(r) : "v"(f), "v"(f));
  return (u16)r;
}
DI float rcp_fast(float x) { return __builtin_amdgcn_rcpf(x); }
DI float exp2_fast(float x) { return __builtin_exp2f(x); }  // v_exp_f32
DI f32x4 mfma16(s16x8 a, s16x8 b, f32x4 c) {
  return __builtin_amdgcn_mfma_f32_16x16x32_bf16(a, b, c, 0, 0, 0);
}

// ---- workspace layout (bytes) ----
#define OFF_COMB   0ull            // u16 [65536][384]  (proc | rus)      50331648
#define OFF_URS    50331648ull     // f32 [32][2048][4] {U, rbar, sbar, 0} 1048576
#define OFF_TPWB   51380736ull     // u16 [256][768]                        393216
#define OFF_WHHB   51773952ull     // u16 [384][128]  (exp2-prescaled)       98304
#define OFF_W1B    51872256ull     // u16 [192][384]                        147456
#define OFF_W2B    52019712ull     // u16 [16][192]                           6144
#define OFF_WABC   52025856ull     // f32 wA[256] wB[256] wC[256]             3072
#define OFF_CABC   52028928ull     // f32 cA cB cC pad                          16
#define OFF_GX     52028944ull     // f32 gxu[384] gxr[384] gxs[384] gxc[384] 6144
// gx rows j<256 (r,z): scaled by -log2e (includes folded b_hh).
// gx rows j>=256 (n): scaled by +2*log2e. whhb rows likewise prescaled.

// =====================================================================
// K0: derived weights + bf16 conversions (with exp2 prescale)
// =====================================================================
__global__ __launch_bounds__(512) void k_prep(
    const float* __restrict__ qw, const float* __restrict__ qb,
    const float* __restrict__ kw, const float* __restrict__ kb,
    const float* __restrict__ vw, const float* __restrict__ vb,
    const float* __restrict__ wih, const float* __restrict__ bih,
    const float* __restrict__ bhh,
    const float* __restrict__ tpw, const float* __restrict__ whh,
    const float* __restrict__ w1, const float* __restrict__ w2,
    u16* __restrict__ tpwb, u16* __restrict__ whhb,
    u16* __restrict__ w1b, u16* __restrict__ w2b,
    float* __restrict__ wabc, float* __restrict__ cabc, float* __restrict__ gx) {
  const int tid = threadIdx.x, bid = blockIdx.x;
  if (bid == 0 && tid < 256) {
    int p = tid;
    float a = 0.f, b = 0.f, c = 0.f;
    for (int j = 0; j < 64; j++) {
      float q = qw[j * 256 + p];
      a += q * kw[2 * j]; b += q * kw[2 * j + 1]; c += q * kb[j];
    }
    wabc[p] = a; wabc[256 + p] = b; wabc[512 + p] = c;
    if (p == 0) {
      float ca = 0.f, cb = 0.f, cc = 0.f;
      for (int j = 0; j < 64; j++) {
        ca += qb[j] * kw[2 * j]; cb += qb[j] * kw[2 * j + 1]; cc += qb[j] * kb[j];
      }
      cabc[0] = ca; cabc[1] = cb; cabc[2] = cc; cabc[3] = 0.f;
    }
  }
  if (bid == 1 && tid < 384) {
    int j = tid;
    float r = 0.f, s = 0.f, c0 = 0.f;
    for (int v = 0; v < 64; v++) {
      float w = wih[j * 65 + 1 + v];
      r += w * vw[2 * v]; s += w * vw[2 * v + 1]; c0 += w * vb[v];
    }
    float xc = c0 + bih[j] + (j < 256 ? bhh[j] : 0.f);
    float sc = (j < 256) ? -L2E : L2E2;
    gx[j] = wih[j * 65] * sc; gx[384 + j] = r * sc;
    gx[768 + j] = s * sc;     gx[1152 + j] = xc * sc;
  }
  const int n1 = 768 * 256, n2 = 384 * 128, n3 = 192 * 384, n4 = 16 * 192;
  const int total = n1 + n2 + n3 + n4;
  for (int i = bid * blockDim.x + tid; i < total; i += gridDim.x * blockDim.x) {
    if (i < n1) tpwb[i] = f2b(tpw[i]);
    else if (i < n1 + n2) {
      int loc = i - n1;                        // row = loc>>7 in [0,384)
      float sc = (loc < 256 * 128) ? L2E : L2E2;
      whhb[loc] = f2b(whh[loc] * sc);
    }
    else if (i < n1 + n2 + n3) w1b[i - n1 - n2] = f2b(w1[i - n1 - n2]);
    else w2b[i - n1 - n2 - n3] = f2b(w2[i - n1 - n2 - n3]);
  }
}

// =====================================================================
// K1: processed = relu(TE @ tp_w.T + tp_b)  -> comb[:, 0:256] (bf16)
// 128x256 tile per block, BK=64, bf16 MFMA, XOR-swizzled LDS
// =====================================================================
__global__ __launch_bounds__(512, 1) void k_gemm1(
    const float* __restrict__ te, const float* __restrict__ tpb,
    const u16* __restrict__ tpwb, u16* __restrict__ comb) {
  __shared__ u16 Als[128 * 64];
  __shared__ u16 Bls[256 * 64];
  const int tid = threadIdx.x;
  const int lane = tid & 63, w = tid >> 6;
  const int c = lane & 15, g4 = lane >> 4;
  const int wm = w >> 2, wn = w & 3;
  const long row0 = (long)blockIdx.x * 128;

  f32x4 acc[4][4];
  #pragma unroll
  for (int i = 0; i < 4; i++)
    #pragma unroll
    for (int j = 0; j < 4; j++) acc[i][j] = (f32x4)(0.f);

  for (int kk = 0; kk < 12; kk++) {
    // stage A (fp32 -> bf16 inline)
    #pragma unroll
    for (int ii = 0; ii < 2; ii++) {
      int idx = tid + 512 * ii;
      int row = idx >> 3, kb = idx & 7;
      const float* g = te + (row0 + row) * 768 + kk * 64 + kb * 8;
      f32x4 p0 = *(const f32x4*)g;
      f32x4 p1 = *(const f32x4*)(g + 4);
      s16x8 v;
      v[0] = f2b(p0[0]); v[1] = f2b(p0[1]); v[2] = f2b(p0[2]); v[3] = f2b(p0[3]);
      v[4] = f2b(p1[0]); v[5] = f2b(p1[1]); v[6] = f2b(p1[2]); v[7] = f2b(p1[3]);
      *(s16x8*)&Als[row * 64 + ((kb ^ (row & 7)) << 3)] = v;
    }
    // stage B
    #pragma unroll
    for (int ii = 0; ii < 4; ii++) {
      int idx = tid + 512 * ii;
      int n = idx >> 3, kb = idx & 7;
      s16x8 v = *(const s16x8*)(tpwb + n * 768 + kk * 64 + kb * 8);
      *(s16x8*)&Bls[n * 64 + ((kb ^ (n & 7)) << 3)] = v;
    }
    __syncthreads();
    #pragma unroll
    for (int kt = 0; kt < 2; kt++) {
      s16x8 af[4], bf[4];
      #pragma unroll
      for (int mt = 0; mt < 4; mt++) {
        int row = wm * 64 + mt * 16 + c;
        af[mt] = *(const s16x8*)&Als[row * 64 + (((kt * 4 + g4) ^ (row & 7)) << 3)];
      }
      #pragma unroll
      for (int nt = 0; nt < 4; nt++) {
        int n = wn * 64 + nt * 16 + c;
        bf[nt] = *(const s16x8*)&Bls[n * 64 + (((kt * 4 + g4) ^ (n & 7)) << 3)];
      }
      #pragma unroll
      for (int mt = 0; mt < 4; mt++)
        #pragma unroll
        for (int nt = 0; nt < 4; nt++)
          acc[mt][nt] = mfma16(af[mt], bf[nt], acc[mt][nt]);
    }
    __syncthreads();
  }
  #pragma unroll
  for (int nt = 0; nt < 4; nt++) {
    int col = wn * 64 + nt * 16 + c;
    float bias = tpb[col];
    #pragma unroll
    for (int mt = 0; mt < 4; mt++)
      #pragma unroll
      for (int r = 0; r < 4; r++) {
        long row = row0 + wm * 64 + mt * 16 + g4 * 4 + r;
        float v = fmaxf(acc[mt][nt][r] + bias, 0.f);
        comb[row * 384 + col] = f2b(v);
      }
  }
}

// =====================================================================
// K2: collapsed attention. Per token: 3 dots of 256, softmax over 3
// "others", emit (U, rbar, sbar). One wave per token.
// =====================================================================
__global__ __launch_bounds__(256) void k_attn(
    const u16* __restrict__ comb, const float* __restrict__ U,
    const float* __restrict__ R, const float* __restrict__ S,
    const float* __restrict__ wabc, const float* __restrict__ cabc,
    float* __restrict__ urs) {
  const int lane = threadIdx.x & 63;
  const long token = (long)blockIdx.x * 4 + (threadIdx.x >> 6);
  const int t = (int)(token & 2047);
  const int seq = (int)(token >> 11);
  const int m = seq & 3;

  u32x2 pv = *(const u32x2*)(comb + token * 384 + lane * 4);
  float p0 = __builtin_bit_cast(float, pv[0] << 16);
  float p1 = __builtin_bit_cast(float, pv[0] & 0xffff0000u);
  float p2 = __builtin_bit_cast(float, pv[1] << 16);
  float p3 = __builtin_bit_cast(float, pv[1] & 0xffff0000u);
  f32x4 wa = *(const f32x4*)(wabc + lane * 4);
  f32x4 wb = *(const f32x4*)(wabc + 256 + lane * 4);
  f32x4 wc = *(const f32x4*)(wabc + 512 + lane * 4);
  float a = p0 * wa[0] + p1 * wa[1] + p2 * wa[2] + p3 * wa[3];
  float b = p0 * wb[0] + p1 * wb[1] + p2 * wb[2] + p3 * wb[3];
  float cd = p0 * wc[0] + p1 * wc[1] + p2 * wc[2] + p3 * wc[3];
  #pragma unroll
  for (int off = 32; off; off >>= 1) {
    a += __shfl_xor(a, off); b += __shfl_xor(b, off); cd += __shfl_xor(cd, off);
  }
  a += cabc[0]; b += cabc[1]; cd += cabc[2];

  float rv[3], sv[3], sc[3];
  #pragma unroll
  for (int n = 0; n < 3; n++) {
    int o = n + (n >= m ? 1 : 0);
    long idx = ((long)seq * 4 + o) * 2048 + t;
    rv[n] = R[idx]; sv[n] = S[idx];
    sc[n] = (a * rv[n] + b * sv[n] + cd) * 0.125f;
  }
  float mx = fmaxf(sc[0], fmaxf(sc[1], sc[2]));
  float e0 = __expf(sc[0] - mx), e1 = __expf(sc[1] - mx), e2 = __expf(sc[2] - mx);
  float inv = rcp_fast(e0 + e1 + e2);
  float rb = (e0 * rv[0] + e1 * rv[1] + e2 * rv[2]) * inv;
  float sb = (e0 * sv[0] + e1 * sv[1] + e2 * sv[2]) * inv;
  if (lane == 0) {
    f32x4 v; v[0] = U[token]; v[1] = rb; v[2] = sb; v[3] = 0.f;
    *(f32x4*)(urs + ((long)seq * 2048 + t) * 4) = v;
  }
}

// =====================================================================
// K3: GRU scan. 1 block per sequence (32 blocks), 8 waves (512 thr).
// Wave w owns gate-triple of j-tile w (12 MFMAs/step). Per-step diet:
//  - exp2-prescaled weights: sigmoid = rcp(1+exp2(xq - h2)), no muls/negs
//  - n-gate b_hh seeded through MFMA C operand
//  - x-projections for step t+1 computed mid-step t (off critical path)
//  - unroll 8 + chunk bases: all DS ops use immediate offsets; t&1 = s&1
//  - unmasked same-value LDS writes (g4 groups duplicate h)
//  - 1-op v_cvt_pk_bf16_f32 for h -> bf16
// =====================================================================
__global__ __launch_bounds__(512, 1) void k_gru(
    const u16* __restrict__ whhb, const float* __restrict__ bhh,
    const float* __restrict__ gx, const float* __restrict__ urs,
    u16* __restrict__ comb) {
  __shared__ u16 hbuf[2][128];
  __shared__ u16 hist[2][32][128];   // 16 KB history chunks
  __shared__ float ulds[2049][4];    // 32 KB+16 urs slice (+1 row pad for prefetch)
  const int tid = threadIdx.x;
  const int lane = tid & 63, w = tid >> 6;   // w in 0..7
  const int c = lane & 15, g4 = lane >> 4;
  const int seq = blockIdx.x;

  // one-time bulk load of this sequence's urs slice (contiguous 32 KB)
  for (int i = tid; i < 2048; i += 512)
    *(f32x4*)&ulds[i][0] = *(const f32x4*)(urs + ((long)seq * 2048 + i) * 4);

  const int j = w * 16 + c;                  // this lane's H column (0..127)
  // B-fragments for the three gate rows at column j: n = g*128 + j
  s16x8 bfr[3][4];
  #pragma unroll
  for (int g = 0; g < 3; g++) {
    int n = g * 128 + j;
    #pragma unroll
    for (int kt = 0; kt < 4; kt++)
      bfr[g][kt] = *(const s16x8*)(whhb + n * 128 + kt * 32 + g4 * 8);
  }
  float gxv[3][4];
  #pragma unroll
  for (int g = 0; g < 3; g++) {
    int jj = g * 128 + j;
    gxv[g][0] = gx[jj];        gxv[g][1] = gx[384 + jj];
    gxv[g][2] = gx[768 + jj];  gxv[g][3] = gx[1152 + jj];
  }
  const float bhn = bhh[256 + j] * L2E2;     // scaled n-gate recurrent bias
  const f32x4 nseed = (f32x4)(bhn);          // MFMA C-seed

  if (tid < 128) { hbuf[0][tid] = 0; hbuf[1][tid] = 0; }
  float hprev = 0.f;
  __syncthreads();  // drains the one-time urs preload too

  // prologue: x-projection for t = 0
  float xq0, xq1, xq2;
  {
    f32x4 u0 = *(const f32x4*)&ulds[0][0];
    xq0 = gxv[0][3] + u0[0] * gxv[0][0] + u0[1] * gxv[0][1] + u0[2] * gxv[0][2];
    xq1 = gxv[1][3] + u0[0] * gxv[1][0] + u0[1] * gxv[1][1] + u0[2] * gxv[1][2];
    xq2 = gxv[2][3] + u0[0] * gxv[2][0] + u0[1] * gxv[2][1] + u0[2] * gxv[2][2];
  }

  u16* rbase = comb + (long)seq * 2048 * 384 + 256;
  for (int chunk = 0; chunk < 64; chunk++) {
    const float* up = &ulds[chunk * 32][0];
    u16* hw = &hist[chunk & 1][0][j];
    #pragma unroll 8
    for (int s = 0; s < 32; s++) {
      s16x8 af[4];
      #pragma unroll
      for (int kt = 0; kt < 4; kt++)
        af[kt] = *(const s16x8*)&hbuf[s & 1][kt * 32 + g4 * 8];
      // 6 independent depth-2 MFMA chains (12 MFMAs/wave); n-chain C-seeded
      f32x4 aA[3], aB[3];
      #pragma unroll
      for (int g = 0; g < 3; g++) {
        f32x4 x0 = (f32x4)(0.f);
        f32x4 x1 = (g == 2) ? nseed : (f32x4)(0.f);
        x0 = mfma16(af[0], bfr[g][0], x0);
        x1 = mfma16(af[2], bfr[g][2], x1);
        x0 = mfma16(af[1], bfr[g][1], x0);
        x1 = mfma16(af[3], bfr[g][3], x1);
        aA[g] = x0; aB[g] = x1;
      }
      // next step's x-projection (independent of h; fills MFMA shadow)
      f32x4 un = *(const f32x4*)(up + (s + 1) * 4);
      float nx0 = gxv[0][3] + un[0] * gxv[0][0] + un[1] * gxv[0][1] + un[2] * gxv[0][2];
      float nx1 = gxv[1][3] + un[0] * gxv[1][0] + un[1] * gxv[1][1] + un[2] * gxv[1][2];
      float nx2 = gxv[2][3] + un[0] * gxv[2][0] + un[1] * gxv[2][1] + un[2] * gxv[2][2];
      // gates (exp2 form; xq pre-negated/scaled at prep)
      float hr2 = aA[0][0] + aB[0][0];
      float hz2 = aA[1][0] + aB[1][0];
      float hn2 = aA[2][0] + aB[2][0];       // includes scaled b_hh_n via seed
      float r = rcp_fast(1.f + exp2_fast(xq0 - hr2));
      float z = rcp_fast(1.f + exp2_fast(xq1 - hz2));
      float e = exp2_fast(xq2 + r * hn2);
      float n = __builtin_fmaf(-2.f, rcp_fast(e + 1.f), 1.f);
      float h = z * (hprev - n) + n;
      hprev = h;
      u16 hb = f2b_cvt(h);
      hbuf[(s + 1) & 1][j] = hb;             // same-value dup across g4: benign
      hw[s * 128] = hb;
      __syncthreads();
      xq0 = nx0; xq1 = nx1; xq2 = nx2;
    }
    // flush chunk history: 32 rows x 256 B, coalesced 16 B stores,
    // fire-and-forget (512 threads cover the 8 KB chunk in one shot)
    const int t0 = chunk * 32;
    {
      int row = tid >> 4, part = tid & 15;
      s16x8 v = *(const s16x8*)&hist[chunk & 1][row][part * 8];
      *(s16x8*)(rbase + (long)(t0 + row) * 384 + part * 8) = v;
    }
  }
}

// =====================================================================
// K4: fused MLP: hid = relu(comb @ w1.T + b1) (bf16 via LDS), then
// logits = hid @ w2.T + b2 (fp32 out). 128 rows per block.
// =====================================================================
__global__ __launch_bounds__(512, 1) void k_mlp(
    const u16* __restrict__ comb, const u16* __restrict__ w1b,
    const float* __restrict__ b1, const u16* __restrict__ w2b,
    const float* __restrict__ b2, float* __restrict__ out) {
  __shared__ u16 smem[40960];  // 80 KB
  u16* Als = smem;             // 128x128
  u16* Bls = smem + 16384;     // 192x128
  u16* Hls = smem;             // 128x192 (reuse after barrier)
  const int tid = threadIdx.x;
  const int lane = tid & 63, w = tid >> 6;
  const int c = lane & 15, g4 = lane >> 4;
  const int wm = w >> 2, wn = w & 3;
  const long row0 = (long)blockIdx.x * 128;

  s16x8 w2f[6];
  #pragma unroll
  for (int kt = 0; kt < 6; kt++)
    w2f[kt] = *(const s16x8*)(w2b + c * 192 + kt * 32 + g4 * 8);
  const float b2v = b2[c];

  f32x4 acc[4][3];
  #pragma unroll
  for (int i = 0; i < 4; i++)
    #pragma unroll
    for (int j = 0; j < 3; j++) acc[i][j] = (f32x4)(0.f);

  for (int kc = 0; kc < 3; kc++) {
    #pragma unroll
    for (int ii = 0; ii < 4; ii++) {
      int idx = tid + 512 * ii;
      int row = idx >> 4, kb = idx & 15;
      s16x8 v = *(const s16x8*)(comb + (row0 + row) * 384 + kc * 128 + kb * 8);
      *(s16x8*)&Als[row * 128 + ((kb ^ (row & 7)) << 3)] = v;
    }
    #pragma unroll
    for (int ii = 0; ii < 6; ii++) {
      int idx = tid + 512 * ii;
      int n = idx >> 4, kb = idx & 15;
      s16x8 v = *(const s16x8*)(w1b + n * 384 + kc * 128 + kb * 8);
      *(s16x8*)&Bls[n * 128 + ((kb ^ (n & 7)) << 3)] = v;
    }
    __syncthreads();
    #pragma unroll
    for (int kt = 0; kt < 4; kt++) {
      s16x8 af[4], bf[3];
      #pragma unroll
      for (int mt = 0; mt < 4; mt++) {
        int row = wm * 64 + mt * 16 + c;
        af[mt] = *(const s16x8*)&Als[row * 128 + (((kt * 4 + g4) ^ (row & 7)) << 3)];
      }
      #pragma unroll
      for (int nt = 0; nt < 3; nt++) {
        int n = wn * 48 + nt * 16 + c;
        bf[nt] = *(const s16x8*)&Bls[n * 128 + (((kt * 4 + g4) ^ (n & 7)) << 3)];
      }
      #pragma unroll
      for (int mt = 0; mt < 4; mt++)
        #pragma unroll
        for (int nt = 0; nt < 3; nt++)
          acc[mt][nt] = mfma16(af[mt], bf[nt], acc[mt][nt]);
    }
    __syncthreads();
  }
  // hid -> LDS (bf16, swizzled)
  #pragma unroll
  for (int nt = 0; nt < 3; nt++) {
    int col = wn * 48 + nt * 16 + c;
    float bias = b1[col];
    int cb = col >> 3, cl = col & 7;
    #pragma unroll
    for (int mt = 0; mt < 4; mt++)
      #pragma unroll
      for (int r = 0; r < 4; r++) {
        int row = wm * 64 + mt * 16 + g4 * 4 + r;
        float v = fmaxf(acc[mt][nt][r] + bias, 0.f);
        Hls[row * 192 + ((cb ^ (row & 7)) << 3) + cl] = f2b(v);
      }
  }
  __syncthreads();
  // gemm2: 16 outputs, K=192
  f32x4 a2 = (f32x4)(0.f);
  const int row = w * 16 + c, r7 = row & 7;
  #pragma unroll
  for (int kt = 0; kt < 6; kt++) {
    s16x8 af = *(const s16x8*)&Hls[row * 192 + (((kt * 4 + g4) ^ r7) << 3)];
    a2 = mfma16(af, w2f[kt], a2);
  }
  #pragma unroll
  for (int r = 0; r < 4; r++) {
    long grow = row0 + w * 16 + g4 * 4 + r;
    out[grow * 16 + c] = a2[r] + b2v;
  }
}

// =====================================================================
extern "C" void kernel_launch(void* const* d_in, const int* in_sizes, int n_in,
                              void* d_out, int out_size, void* d_ws, size_t ws_size,
                              hipStream_t stream) {
  (void)in_sizes; (void)n_in; (void)out_size; (void)ws_size;
  const float* te  = (const float*)d_in[0];
  const float* U   = (const float*)d_in[1];
  const float* R   = (const float*)d_in[2];
  const float* S   = (const float*)d_in[3];
  const float* tpw = (const float*)d_in[4];
  const float* tpb = (const float*)d_in[5];
  const float* qw  = (const float*)d_in[6];
  const float* qb  = (const float*)d_in[7];
  const float* kw  = (const float*)d_in[8];
  const float* kb  = (const float*)d_in[9];
  const float* vw  = (const float*)d_in[10];
  const float* vb  = (const float*)d_in[11];
  const float* wih = (const float*)d_in[12];
  const float* whh = (const float*)d_in[13];
  const float* bih = (const float*)d_in[14];
  const float* bhh = (const float*)d_in[15];
  const float* w1  = (const float*)d_in[16];
  const float* b1  = (const float*)d_in[17];
  const float* w2  = (const float*)d_in[18];
  const float* b2  = (const float*)d_in[19];

  char* ws = (char*)d_ws;
  u16*   comb = (u16*)(ws + OFF_COMB);
  float* urs  = (float*)(ws + OFF_URS);
  u16*   tpwb = (u16*)(ws + OFF_TPWB);
  u16*   whhb = (u16*)(ws + OFF_WHHB);
  u16*   w1b  = (u16*)(ws + OFF_W1B);
  u16*   w2b  = (u16*)(ws + OFF_W2B);
  float* wabc = (float*)(ws + OFF_WABC);
  float* cabc = (float*)(ws + OFF_CABC);
  float* gx   = (float*)(ws + OFF_GX);
  float* out  = (float*)d_out;

  hipLaunchKernelGGL(k_prep, dim3(32), dim3(512), 0, stream,
                     qw, qb, kw, kb, vw, vb, wih, bih, bhh, tpw, whh, w1, w2,
                     tpwb, whhb, w1b, w2b, wabc, cabc, gx);
  hipLaunchKernelGGL(k_gemm1, dim3(512), dim3(512), 0, stream, te, tpb, tpwb, comb);
  hipLaunchKernelGGL(k_attn, dim3(16384), dim3(256), 0, stream, comb, U, R, S, wabc, cabc, urs);
  hipLaunchKernelGGL(k_gru, dim3(32), dim3(512), 0, stream, whhb, bhh, gx, urs, comb);
  hipLaunchKernelGGL(k_mlp, dim3(512), dim3(512), 0, stream, comb, w1b, b1, w2b, b2, out);
}